// Round 8
// baseline (21.267 us; speedup 1.0000x reference)
//
#include <hip/hip_runtime.h>

#define NPTS   384
#define DIM    256
#define NT     24            // 16-wide tiles per dim (384/16)
#define NTILE  (NT*NT)       // 576 tiles, one wave each
#define APB2   12            // anchors per K2 block
#define NBLK2  (NPTS/APB2)   // 32 K2 blocks
#define MAXK   64
#define MARGIN 1.0f

typedef __attribute__((ext_vector_type(8))) short bf16x8;
typedef __attribute__((ext_vector_type(4))) float f32x4;

__device__ __forceinline__ unsigned short f2bf(float f) {   // RNE fp32->bf16
    unsigned int u = __float_as_uint(f);
    u += 0x7FFFu + ((u >> 16) & 1u);
    return (unsigned short)(u >> 16);
}
__device__ __forceinline__ float bf2f(unsigned short b) {
    return __uint_as_float(((unsigned int)b) << 16);
}

// K1: one wave per 16x16 tile of D = clamp(n_i + n_j - 2 X.X^T, 0).
// bf16 hi/lo split: 3 MFMA per K=32 step, fp32-grade accuracy.
// Fragment layout = two stacked x16 halves (m156/m162 tr_read evidence):
//   elem e<4: k = 4*(lane>>4)+e ; e>=4: k = 16+4*(lane>>4)+(e-4).
// Norms accumulated in exact fp32 from the loaded values; exchanged via shfl
// (no LDS anywhere in this kernel).
__global__ __launch_bounds__(64) void triplet_dmat(const float* __restrict__ x,
                                                   float* __restrict__ dmat,
                                                   unsigned int* __restrict__ ticket) {
    const int lane = threadIdx.x;          // 64-thread block = one wave
    const int t    = blockIdx.x;
    const int ti   = t / NT, tj = t % NT;
    const int m    = lane & 15;            // operand row this lane loads
    const int g4   = (lane >> 4) * 4;      // k sub-offset within each 16-half

    if (t == 0 && lane == 0) *ticket = 0u; // K2 ticket reset (R5-proven)

    const float* pa = x + (size_t)(ti * 16 + m) * DIM + g4;
    const float* pb = x + (size_t)(tj * 16 + m) * DIM + g4;

    f32x4 acc = {0.f, 0.f, 0.f, 0.f};
    float na = 0.f, nb = 0.f;

    #pragma unroll
    for (int kk = 0; kk < DIM; kk += 32) {
        float a[8], b[8];
        *(float4*)(a)     = *(const float4*)(pa + kk);        // k = kk+g4+0..3
        *(float4*)(a + 4) = *(const float4*)(pa + kk + 16);   // k = kk+16+g4+0..3
        *(float4*)(b)     = *(const float4*)(pb + kk);
        *(float4*)(b + 4) = *(const float4*)(pb + kk + 16);

        bf16x8 Ah, Al, Bh, Bl;
        #pragma unroll
        for (int e = 0; e < 8; ++e) {
            na += a[e] * a[e];
            nb += b[e] * b[e];
            unsigned short h = f2bf(a[e]);
            Ah[e] = (short)h;
            Al[e] = (short)f2bf(a[e] - bf2f(h));
            h = f2bf(b[e]);
            Bh[e] = (short)h;
            Bl[e] = (short)f2bf(b[e] - bf2f(h));
        }
        acc = __builtin_amdgcn_mfma_f32_16x16x32_bf16(Ah, Bh, acc, 0, 0, 0);
        acc = __builtin_amdgcn_mfma_f32_16x16x32_bf16(Al, Bh, acc, 0, 0, 0);
        acc = __builtin_amdgcn_mfma_f32_16x16x32_bf16(Ah, Bl, acc, 0, 0, 0);
    }

    // fold k-chunk partials -> full fp32 row norms (all 4 group-lanes agree)
    na += __shfl_xor(na, 16, 64); na += __shfl_xor(na, 32, 64);
    nb += __shfl_xor(nb, 16, 64); nb += __shfl_xor(nb, 32, 64);

    // C/D layout (m89): col = lane&15, row = (lane>>4)*4 + reg
    #pragma unroll
    for (int r = 0; r < 4; ++r) {
        const int rl = (lane >> 4) * 4 + r;
        const float nar = __shfl(na, rl, 64);   // norm of A-tile row rl
        float d = nar + nb - 2.0f * acc[r];     // nb = norm of B-tile row m (own lane)
        d = fmaxf(d, 0.f);
        dmat[(size_t)(ti * 16 + rl) * NPTS + tj * 16 + m] = d;
    }
}

// K2 (R5-proven, unchanged): 32 blocks x 12 anchors; ballot value-compaction,
// wave-uniform hinge loop, 32-atomic ticket last-block final reduce.
__global__ __launch_bounds__(256) void triplet_hinge(const float* __restrict__ dmat,
                                                     const int* __restrict__ labels,
                                                     float2* __restrict__ partial,
                                                     unsigned int* __restrict__ ticket,
                                                     float* __restrict__ out) {
    const int b    = blockIdx.x;
    const int tid  = threadIdx.x;
    const int lane = tid & 63;
    const int wid  = tid >> 6;

    __shared__ int   lab[NPTS];
    __shared__ float kd[4][MAXK];
    __shared__ float wnum[4], wcnt[4];
    __shared__ int   last_sh;

    for (int j = tid; j < NPTS; j += 256) lab[j] = labels[j];
    __syncthreads();

    float num = 0.f, cnt = 0.f;
    #pragma unroll
    for (int t = 0; t < 3; ++t) {
        const int a  = b * APB2 + wid * 3 + t;
        const int li = lab[a];

        float dr[6];
        #pragma unroll
        for (int c = 0; c < 6; ++c) dr[c] = dmat[(size_t)a * NPTS + c * 64 + lane];

        int base = 0;
        #pragma unroll
        for (int c = 0; c < 6; ++c) {
            const bool mt = (lab[c * 64 + lane] == li);
            const unsigned long long mk = __ballot(mt);
            const int pre = __popcll(mk & ((1ull << lane) - 1ull));
            const int p = base + pre;
            if (mt && p < MAXK) kd[wid][p] = dr[c];
            base += __popcll(mk);       // wave-uniform
        }
        const int nk = (base > MAXK) ? MAXK : base;

        #pragma unroll
        for (int c = 0; c < 6; ++c) {
            const int j = c * 64 + lane;
            if (lab[j] != li) {
                const float bb = dr[c] - MARGIN;
                for (int t2 = 0; t2 < nk; ++t2) {
                    const float h = bb + kd[wid][t2];   // wave-uniform broadcast
                    num += (h > 0.f) ? h : 0.f;
                }
                cnt += (float)nk;
            }
        }
    }

    #pragma unroll
    for (int mm = 1; mm < 64; mm <<= 1) {
        num += __shfl_xor(num, mm, 64);
        cnt += __shfl_xor(cnt, mm, 64);
    }
    if (lane == 0) { wnum[wid] = num; wcnt[wid] = cnt; }
    __syncthreads();

    if (tid == 0) {
        partial[b] = make_float2(wnum[0] + wnum[1] + wnum[2] + wnum[3],
                                 wcnt[0] + wcnt[1] + wcnt[2] + wcnt[3]);
        __threadfence();
        const unsigned int old = atomicAdd(ticket, 1u);   // 32 RMWs total
        last_sh = (old == NBLK2 - 1) ? 1 : 0;
    }
    __syncthreads();

    if (last_sh && tid < 64) {
        __threadfence();
        float n = 0.f, c = 0.f;
        if (tid < NBLK2) { const float2 v = partial[tid]; n = v.x; c = v.y; }
        #pragma unroll
        for (int mm = 1; mm < 32; mm <<= 1) {
            n += __shfl_xor(n, mm, 64);
            c += __shfl_xor(c, mm, 64);
        }
        if (tid == 0) out[0] = n / c;
    }
}

extern "C" void kernel_launch(void* const* d_in, const int* in_sizes, int n_in,
                              void* d_out, int out_size, void* d_ws, size_t ws_size,
                              hipStream_t stream) {
    const float* x      = (const float*)d_in[0];
    const int*   labels = (const int*)d_in[1];
    float*       out    = (float*)d_out;

    float*        dmat    = (float*)d_ws;                                    // 590 KB
    float2*       partial = (float2*)((char*)d_ws + (size_t)NPTS * NPTS * sizeof(float));
    unsigned int* ticket  = (unsigned int*)(partial + NBLK2);

    triplet_dmat<<<NTILE, 64, 0, stream>>>(x, dmat, ticket);
    triplet_hinge<<<NBLK2, 256, 0, stream>>>(dmat, labels, partial, ticket, out);
}

// Round 9
// 17.337 us; speedup vs baseline: 1.2267x; 1.2267x over previous
//
#include <hip/hip_runtime.h>

#define NPTS   384
#define DIM    256
#define GA     4              // anchors per block (register-resident fragments)
#define NGRP   (NPTS/GA)      // 96 anchor groups
#define SPLIT  8              // j-slices
#define JS     (NPTS/SPLIT)   // 48 j's per block
#define NBLK   (NGRP*SPLIT)   // 768 blocks = 3/CU
#define MAXK   64             // cap on same-class count (expected ~12)
#define MARGIN 1.0f

__device__ __forceinline__ float wave_red_sum(float p) {
    #pragma unroll
    for (int m = 1; m < 64; m <<= 1) p += __shfl_xor(p, m, 64);
    return p;
}

// Block (g, s): anchors a0..a0+3, j-slice s (48 rows). Fully fused:
//  - 4 anchor fragments in registers (64 VGPR); every slice row read ONCE and
//    dotted vs all 4 anchors (4x reuse, 4x load ILP vs R6)
//  - wave w ballot-compacts positives of anchor a0+w (global label reads,
//    before the first barrier)
//  - positive dots per anchor by 16-lane groups
//  - fused hinge over 192 (a, j) pairs -> one float2 partial per block
__global__ __launch_bounds__(256) void triplet_main(const float* __restrict__ x,
                                                    const int* __restrict__ labels,
                                                    float2* __restrict__ partial) {
    const int g    = blockIdx.x;
    const int s    = blockIdx.y;
    const int tid  = threadIdx.x;
    const int lane = tid & 63;
    const int wid  = tid >> 6;
    const int sub  = lane >> 4;   // row within 4-row group
    const int l16  = lane & 15;   // element-slice lane
    const int a0   = g * GA;

    __shared__ int   lab[NPTS];
    __shared__ int   kidx[GA][MAXK];
    __shared__ float dk[GA][MAXK];
    __shared__ float dj[GA][JS];
    __shared__ int   nk_sh[GA];
    __shared__ float wnum[4], wcnt[4];

    // stage labels for the hinge phase (all threads, strided)
    for (int j = tid; j < NPTS; j += 256) lab[j] = labels[j];

    // anchor fragments: fa[t][q] = x[a0+t][l16*4 + q*64 .. +4)
    float4 fa[GA][4];
    #pragma unroll
    for (int t = 0; t < GA; ++t)
        #pragma unroll
        for (int q = 0; q < 4; ++q)
            fa[t][q] = *(const float4*)(x + (size_t)(a0 + t) * DIM + l16 * 4 + q * 64);

    // wave w: ballot-compact positives of anchor a0+w (global label reads)
    {
        const int li = labels[a0 + wid];
        int base = 0;
        #pragma unroll
        for (int c = 0; c < 6; ++c) {
            const bool m = (labels[c * 64 + lane] == li);
            const unsigned long long mk = __ballot(m);
            const int pre = __popcll(mk & ((1ull << lane) - 1ull));
            const int p = base + pre;
            if (m && p < MAXK) kidx[wid][p] = c * 64 + lane;
            base += __popcll(mk);          // wave-uniform
        }
        if (lane == 0) nk_sh[wid] = (base > MAXK) ? MAXK : base;
    }
    __syncthreads();

    // slice dots: 16 rows/block-iter, 3 iters; one row load -> 4 anchor dots
    #pragma unroll
    for (int u = 0; u < JS / 16; ++u) {
        const int rl = u * 16 + wid * 4 + sub;           // 0..47
        const float* xr = x + (size_t)(s * JS + rl) * DIM + l16 * 4;
        float4 rx[4];
        #pragma unroll
        for (int q = 0; q < 4; ++q) rx[q] = *(const float4*)(xr + q * 64);
        #pragma unroll
        for (int t = 0; t < GA; ++t) {
            float acc = 0.f;
            #pragma unroll
            for (int q = 0; q < 4; ++q) {
                const float d0 = rx[q].x - fa[t][q].x, d1 = rx[q].y - fa[t][q].y,
                            d2 = rx[q].z - fa[t][q].z, d3 = rx[q].w - fa[t][q].w;
                acc += d0*d0 + d1*d1 + d2*d2 + d3*d3;
            }
            #pragma unroll
            for (int m = 1; m < 16; m <<= 1) acc += __shfl_xor(acc, m, 64);
            if (l16 == 0) dj[t][rl] = acc;
        }
    }

    // positive dots: 16 groups (wid,sub) cover each anchor's list (1 iter typ.)
    #pragma unroll
    for (int a = 0; a < GA; ++a) {
        const int nk = nk_sh[a];
        for (int t0 = 0; t0 < nk; t0 += 16) {
            const int t = t0 + wid * 4 + sub;
            if (t < nk) {                    // whole 16-lane group together
                const float* xr = x + (size_t)kidx[a][t] * DIM + l16 * 4;
                float acc = 0.f;
                #pragma unroll
                for (int q = 0; q < 4; ++q) {
                    const float4 rv = *(const float4*)(xr + q * 64);
                    const float d0 = rv.x - fa[a][q].x, d1 = rv.y - fa[a][q].y,
                                d2 = rv.z - fa[a][q].z, d3 = rv.w - fa[a][q].w;
                    acc += d0*d0 + d1*d1 + d2*d2 + d3*d3;
                }
                #pragma unroll
                for (int m = 1; m < 16; m <<= 1) acc += __shfl_xor(acc, m, 64);
                if (l16 == 0) dk[a][t] = acc;
            }
        }
    }
    __syncthreads();

    // hinge: 192 (a, jl) pairs, threads 0..191
    float num = 0.f, cnt = 0.f;
    if (tid < GA * JS) {
        const int a  = tid / JS;
        const int jl = tid % JS;
        const int li = lab[a0 + a];
        if (lab[s * JS + jl] != li) {
            const int nk = nk_sh[a];
            const float b = dj[a][jl] - MARGIN;
            for (int t = 0; t < nk; ++t) {
                const float h = b + dk[a][t];   // <=2 addresses per wave: free
                num += (h > 0.f) ? h : 0.f;
            }
            cnt = (float)nk;
        }
    }
    num = wave_red_sum(num);
    cnt = wave_red_sum(cnt);
    if (lane == 0) { wnum[wid] = num; wcnt[wid] = cnt; }
    __syncthreads();
    if (tid == 0)
        partial[blockIdx.y * gridDim.x + blockIdx.x] =
            make_float2(wnum[0] + wnum[1] + wnum[2] + wnum[3],
                        wcnt[0] + wcnt[1] + wcnt[2] + wcnt[3]);
}

__global__ __launch_bounds__(256) void triplet_finalize(const float2* __restrict__ partial,
                                                        float* __restrict__ out) {
    const int tid = threadIdx.x, lane = tid & 63, wid = tid >> 6;
    __shared__ float wnum[4], wcnt[4];
    float n = 0.f, c = 0.f;
    for (int p = tid; p < NBLK; p += 256) {
        const float2 v = partial[p];
        n += v.x; c += v.y;
    }
    n = wave_red_sum(n);
    c = wave_red_sum(c);
    if (lane == 0) { wnum[wid] = n; wcnt[wid] = c; }
    __syncthreads();
    if (tid == 0)
        out[0] = (wnum[0] + wnum[1] + wnum[2] + wnum[3]) /
                 (wcnt[0] + wcnt[1] + wcnt[2] + wcnt[3]);
}

extern "C" void kernel_launch(void* const* d_in, const int* in_sizes, int n_in,
                              void* d_out, int out_size, void* d_ws, size_t ws_size,
                              hipStream_t stream) {
    const float* x      = (const float*)d_in[0];
    const int*   labels = (const int*)d_in[1];
    float*       out    = (float*)d_out;

    float2* partial = (float2*)d_ws;

    dim3 grid(NGRP, SPLIT);
    triplet_main<<<grid, 256, 0, stream>>>(x, labels, partial);
    triplet_finalize<<<1, 256, 0, stream>>>(partial, out);
}